// Round 16
// baseline (110.162 us; speedup 1.0000x reference)
//
#include <hip/hip_runtime.h>

typedef unsigned int u32;
typedef unsigned short u16;
typedef short bf16x8 __attribute__((ext_vector_type(8)));
typedef float f32x4 __attribute__((ext_vector_type(4)));
typedef float f32x8 __attribute__((ext_vector_type(8)));
typedef float f32x16 __attribute__((ext_vector_type(16)));
typedef int i32x4 __attribute__((ext_vector_type(4)));
typedef __bf16 bf16x2 __attribute__((ext_vector_type(2)));
typedef float f32x2 __attribute__((ext_vector_type(2)));
typedef _Float16 f16x2t __attribute__((ext_vector_type(2)));
typedef _Float16 f16x8 __attribute__((ext_vector_type(8)));

#define KSPLIT 8

// round-to-nearest-even f32 -> bf16 (bit trick, finite values)
__device__ __forceinline__ u32 pack2bf(float a, float b) {
    u32 ua = __float_as_uint(a), ub = __float_as_uint(b);
    ua = (ua + 0x7fffu + ((ua >> 16) & 1u)) >> 16;
    ub = (ub + 0x7fffu + ((ub >> 16) & 1u)) >> 16;
    return (ua & 0xffffu) | (ub << 16);
}
__device__ __forceinline__ u16 bf1(float a) {
    u32 ua = __float_as_uint(a);
    return (u16)((ua + 0x7fffu + ((ua >> 16) & 1u)) >> 16);
}
// pair convert: compiler emits v_cvt_pk_bf16_f32 (RNE)
__device__ __forceinline__ u32 b2(float a, float b) {
    f32x2 f; f[0] = a; f[1] = b;
    bf16x2 h = __builtin_convertvector(f, bf16x2);
    return __builtin_bit_cast(u32, h);
}
// pair convert f32 -> f16 (RNE)
__device__ __forceinline__ u32 h2(float a, float b) {
    f32x2 f; f[0] = a; f[1] = b;
    f16x2t h = __builtin_convertvector(f, f16x2t);
    return __builtin_bit_cast(u32, h);
}

// ---------------- K0: all four weights f32 -> bf16 in one launch ----------------
__global__ __launch_bounds__(256) void cvt_w4(const float* __restrict__ wq,
                                              const float* __restrict__ wk,
                                              const float* __restrict__ wv,
                                              const float* __restrict__ wp,
                                              u16* __restrict__ dst) {
    int i = blockIdx.x * 256 + threadIdx.x;   // 65536 float4-chunks total
    int which = i >> 14;
    int j = i & 16383;
    const float* s = which == 0 ? wq : which == 1 ? wk : which == 2 ? wv : wp;
    float4 a = ((const float4*)s)[j];
    uint2 v;
    v.x = pack2bf(a.x, a.y);
    v.y = pack2bf(a.z, a.w);
    ((uint2*)(dst + which * 65536))[j] = v;
}

// ---------------- K1: projections, flattened grid (64 Q + 128 K + 128 V blocks) ----
// mode 0: Qb = (scale*log2e) * xq @ Wq^T   [row][256]
// mode 1: K2 = xk @ Wk^T                    [b][h][n][32]  (attn layout, direct)
// mode 2: V2 = xv @ Wv^T                    [b][h][s32][32d][32pk], pk = key with
//         bits 2<->3 swapped (matches 32x32x16 PV B-fragment key ownership)
// Modes 0/1 use OPERAND-SWAPPED MFMA (C^T): thread owns X-row (m0+w*16+lq) and
// 4 consecutive output dims d = nt*16+g*4+r -> vectorized uint2 stores.
__global__ __launch_bounds__(256) void proj_all(const float* __restrict__ xq,
                                                const float* __restrict__ xk,
                                                const float* __restrict__ xv,
                                                const u16* __restrict__ W4,
                                                u16* __restrict__ Qb,
                                                u16* __restrict__ K2,
                                                u16* __restrict__ V2,
                                                float qalpha) {
    int bx = blockIdx.x;
    int mode = bx < 64 ? 0 : (bx < 192 ? 1 : 2);
    int xb = mode == 0 ? bx : (mode == 1 ? bx - 64 : bx - 192);
    const float* X = mode == 0 ? xq : mode == 1 ? xk : xv;
    const u16* Wb = W4 + mode * 65536;

    __shared__ u16 xs[64 * 256];
    int t = threadIdx.x;
    int m0 = xb * 64;
#pragma unroll
    for (int i = 0; i < 8; i++) {
        int c16 = t + 256 * i;
        int row = c16 >> 5, col16 = c16 & 31;
        const float4* src = (const float4*)(X + (size_t)(m0 + row) * 256 + col16 * 8);
        float4 a = src[0], b2v = src[1];
        uint4 v;
        v.x = pack2bf(a.x, a.y); v.y = pack2bf(a.z, a.w);
        v.z = pack2bf(b2v.x, b2v.y); v.w = pack2bf(b2v.z, b2v.w);
        int byteoff = row * 512 + ((col16 * 16) ^ ((row & 7) << 4));
        *(uint4*)((char*)xs + byteoff) = v;
    }
    __syncthreads();
    int lane = t & 63, w = t >> 6;
    int lq = lane & 15, g = lane >> 4;
    int rowA = w * 16 + lq;
    f32x4 acc[16];
    f32x4 z = {0.f, 0.f, 0.f, 0.f};
#pragma unroll
    for (int nt = 0; nt < 16; nt++) acc[nt] = z;
    if (mode < 2) {
        // swapped: C^T[d][m]; A = W fragment, B = X fragment (layouts symmetric)
#pragma unroll
        for (int kk = 0; kk < 8; kk++) {
            bf16x8 aF = *(const bf16x8*)((const char*)xs + rowA * 512 +
                                         ((kk * 64 + g * 16) ^ ((rowA & 7) << 4)));
#pragma unroll
            for (int nt = 0; nt < 16; nt++) {
                bf16x8 bF = *(const bf16x8*)(Wb + (size_t)(nt * 16 + lq) * 256 + kk * 32 + g * 8);
                acc[nt] = __builtin_amdgcn_mfma_f32_16x16x32_bf16(bF, aF, acc[nt], 0, 0, 0);
            }
        }
    } else {
#pragma unroll
        for (int kk = 0; kk < 8; kk++) {
            bf16x8 aF = *(const bf16x8*)((const char*)xs + rowA * 512 +
                                         ((kk * 64 + g * 16) ^ ((rowA & 7) << 4)));
#pragma unroll
            for (int nt = 0; nt < 16; nt++) {
                bf16x8 bF = *(const bf16x8*)(Wb + (size_t)(nt * 16 + lq) * 256 + kk * 32 + g * 8);
                acc[nt] = __builtin_amdgcn_mfma_f32_16x16x32_bf16(aF, bF, acc[nt], 0, 0, 0);
            }
        }
    }
    if (mode == 0) {
        int mrow = m0 + w * 16 + lq;
        u16* dst = Qb + (size_t)mrow * 256 + g * 4;
#pragma unroll
        for (int nt = 0; nt < 16; nt++) {
            uint2 v;
            v.x = pack2bf(acc[nt][0] * qalpha, acc[nt][1] * qalpha);
            v.y = pack2bf(acc[nt][2] * qalpha, acc[nt][3] * qalpha);
            *(uint2*)(dst + nt * 16) = v;
        }
    } else if (mode == 1) {
        int m = m0 + w * 16 + lq;
        int b = m >> 12, n = m & 4095;
#pragma unroll
        for (int nt = 0; nt < 16; nt++) {
            int d = nt * 16 + g * 4;           // 4-aligned, never crosses 32-boundary
            int h = d >> 5, d32 = d & 31;
            uint2 v;
            v.x = pack2bf(acc[nt][0], acc[nt][1]);
            v.y = pack2bf(acc[nt][2], acc[nt][3]);
            *(uint2*)(K2 + ((size_t)(b * 8 + h) * 4096 + n) * 32 + d32) = v;
        }
    } else {
        // V: keys m..m+3 at dim d -> permuted tile store (swap bits 2,3 of key&31)
        int m = m0 + w * 16 + g * 4;
        int b = m >> 12, n = m & 4095;
        int s = n >> 5;
        int t5 = n & 31;                                   // bits 0,1 are zero
        int pklo = (t5 & 19) | ((t5 << 1) & 8) | ((t5 >> 1) & 4);
#pragma unroll
        for (int nt = 0; nt < 16; nt++) {
            int d = nt * 16 + lq;
            int h = d >> 5, d32 = d & 31;
            uint2 v;
            v.x = pack2bf(acc[nt][0], acc[nt][1]);
            v.y = pack2bf(acc[nt][2], acc[nt][3]);
            *(uint2*)(V2 + ((((size_t)(b * 8 + h) * 128 + s) * 32 + d32) * 32 + pklo)) = v;
        }
    }
}

// ---------------- K2g: attn_save = (Qb . K^T) * 0.125*ln2, f32 out (runs LAST) ----
// 32x32x16 MFMA, depth-1 register prefetch over kk.
// K-dim 256 = 16 steps; head h = kk>>1, within-head offset (kk&1)*16.
// 1-D grid with XCD swizzle: chunk of 128 consecutive tiles per XCD (1024%8==0).
__global__ __launch_bounds__(256) void save_gemm(const u16* __restrict__ Qb,
                                                 const u16* __restrict__ K2,
                                                 float* __restrict__ sv) {
    const float SAVE = 0.125f * 0.69314718055994530942f;
    int id = blockIdx.x;                       // 0..1023
    int sw = (id & 7) * 128 + (id >> 3);       // bijective XCD chunking
    int b = sw >> 9;
    int r = sw & 511;
    int m0 = (r >> 5) * 128;                   // 16 m-tiles of 128
    int n0 = (r & 31) * 128;                   // 32 n-tiles of 128
    int t = threadIdx.x, lane = t & 63, wv = t >> 6;
    int wr = wv >> 1, wc = wv & 1;
    int l32 = lane & 31, hl = lane >> 5;
    const u16* Q = Qb + (size_t)b * 2048 * 256;
    const u16* Kb = K2 + (size_t)b * 8 * 4096 * 32;
    const u16* Abase = Q + (size_t)(m0 + wr * 64 + l32) * 256 + hl * 8;
    const u16* Bbase = Kb + (size_t)(n0 + wc * 64 + l32) * 32 + hl * 8;
    f32x16 acc[2][2];
    f32x16 z16 = {};
#pragma unroll
    for (int mt = 0; mt < 2; mt++)
#pragma unroll
        for (int nt = 0; nt < 2; nt++) acc[mt][nt] = z16;
    bf16x8 aF0 = *(const bf16x8*)(Abase);
    bf16x8 aF1 = *(const bf16x8*)(Abase + 32 * 256);
    bf16x8 bF0 = *(const bf16x8*)(Bbase);
    bf16x8 bF1 = *(const bf16x8*)(Bbase + 32 * 32);
#pragma unroll
    for (int kk = 0; kk < 16; kk++) {
        int nx = kk < 15 ? kk + 1 : 15;
        const u16* na = Abase + nx * 16;
        const u16* nb = Bbase + (size_t)(nx >> 1) * 131072 + (nx & 1) * 16;
        bf16x8 a0 = *(const bf16x8*)(na);
        bf16x8 a1 = *(const bf16x8*)(na + 32 * 256);
        bf16x8 b0 = *(const bf16x8*)(nb);
        bf16x8 b1 = *(const bf16x8*)(nb + 32 * 32);
        __builtin_amdgcn_s_setprio(1);
        acc[0][0] = __builtin_amdgcn_mfma_f32_32x32x16_bf16(aF0, bF0, acc[0][0], 0, 0, 0);
        acc[0][1] = __builtin_amdgcn_mfma_f32_32x32x16_bf16(aF0, bF1, acc[0][1], 0, 0, 0);
        acc[1][0] = __builtin_amdgcn_mfma_f32_32x32x16_bf16(aF1, bF0, acc[1][0], 0, 0, 0);
        acc[1][1] = __builtin_amdgcn_mfma_f32_32x32x16_bf16(aF1, bF1, acc[1][1], 0, 0, 0);
        __builtin_amdgcn_s_setprio(0);
        aF0 = a0; aF1 = a1; bF0 = b0; bF1 = b1;
    }
#pragma unroll
    for (int mt = 0; mt < 2; mt++) {
#pragma unroll
        for (int nt = 0; nt < 2; nt++) {
            int col = n0 + wc * 64 + nt * 32 + l32;
#pragma unroll
            for (int rg = 0; rg < 16; rg++) {
                int row = m0 + wr * 64 + mt * 32 + (rg & 3) + 8 * (rg >> 2) + 4 * hl;
                sv[((size_t)b * 2048 + row) * 4096 + col] = acc[mt][nt][rg] * SAVE;
            }
        }
    }
}

// ---------------- K3: flash attention partial, 32x32x16 MFMA, 64 q/wave --------------
// 1-D grid 1024 blocks (id&7 = h -> XCD-local K/V), 256 thr. Wave: 64 q (2 groups
// of 32), 512 keys (KSPLIT=8 -> 4096 waves, ~3-4 waves/SIMD; K/V traffic unchanged
// vs KSPLIT=4 since q/wave kept at 64). No LDS/barriers/max; exp2 direct.
// Depth-1 register prefetch of next subtile's K/V fragments. l via ones-A MFMA.
__global__ __launch_bounds__(256, 2) void attn_part(const u16* __restrict__ Qb,
                                                    const u16* __restrict__ K2,
                                                    const u16* __restrict__ V2,
                                                    _Float16* __restrict__ PO,
                                                    float* __restrict__ PL) {
    int id = blockIdx.x;
    int h = id & 7;
    int r0 = id >> 3;                         // 0..127
    int qblk = r0 & 7;
    int b = (r0 >> 3) & 1;
    int part = r0 >> 4;                       // 0..7
    int bh = b * 8 + h;
    int t = threadIdx.x, lane = t & 63, w = t >> 6;
    int lq = lane & 31, hl = lane >> 5;
    int qa = qblk * 256 + w * 64 + lq;        // group 0; group 1 = qa+32
    const u16* Qrow = Qb + ((size_t)(b * 2048 + qa)) * 256 + h * 32 + hl * 8;
    bf16x8 qf00 = *(const bf16x8*)(Qrow);
    bf16x8 qf01 = *(const bf16x8*)(Qrow + 16);
    bf16x8 qf10 = *(const bf16x8*)(Qrow + 32 * 256);
    bf16x8 qf11 = *(const bf16x8*)(Qrow + 32 * 256 + 16);
    const u16* Kh = K2 + ((size_t)bh * 4096 + part * 512 + lq) * 32 + hl * 8;
    const u16* Vh = V2 + (size_t)bh * 131072 + part * 16384 + lq * 32 + hl * 8;
    f32x16 z16 = {};
    f32x16 o0 = z16, o1 = z16, laa = z16, lab = z16;
    const short ONE = (short)0x3F80;          // bf16 1.0
    bf16x8 onesF = {ONE, ONE, ONE, ONE, ONE, ONE, ONE, ONE};
    // subtile i (i=0..15): keys [i*32, i*32+32). K stride 1024 u16, V stride 1024 u16.
    bf16x8 kf0 = *(const bf16x8*)(Kh);
    bf16x8 kf1 = *(const bf16x8*)(Kh + 16);
    bf16x8 vf0 = *(const bf16x8*)(Vh);
    bf16x8 vf1 = *(const bf16x8*)(Vh + 16);
    for (int i = 0; i < 16; ++i) {
        // prefetch subtile i+1 (clamped; last iter reloads i=15, harmless)
        int nx = i < 15 ? i + 1 : 15;
        const u16* nkp = Kh + nx * 1024;
        const u16* nvp = Vh + nx * 1024;
        bf16x8 nk0 = *(const bf16x8*)(nkp);
        bf16x8 nk1 = *(const bf16x8*)(nkp + 16);
        bf16x8 nv0 = *(const bf16x8*)(nvp);
        bf16x8 nv1 = *(const bf16x8*)(nvp + 16);
        // S^T tiles (32 keys x 32 q), K-dim = d
        f32x16 sA = __builtin_amdgcn_mfma_f32_32x32x16_bf16(kf0, qf00, z16, 0, 0, 0);
        sA = __builtin_amdgcn_mfma_f32_32x32x16_bf16(kf1, qf01, sA, 0, 0, 0);
        f32x16 sB = __builtin_amdgcn_mfma_f32_32x32x16_bf16(kf0, qf10, z16, 0, 0, 0);
        sB = __builtin_amdgcn_mfma_f32_32x32x16_bf16(kf1, qf11, sB, 0, 0, 0);
        // p = exp2(S), pack to PV B-fragments
        float pA[16], pB[16];
#pragma unroll
        for (int k = 0; k < 16; k++) pA[k] = __builtin_amdgcn_exp2f(sA[k]);
#pragma unroll
        for (int k = 0; k < 16; k++) pB[k] = __builtin_amdgcn_exp2f(sB[k]);
        i32x4 wa0, wa1, wb0, wb1;
#pragma unroll
        for (int j = 0; j < 4; j++) {
            wa0[j] = (int)b2(pA[2 * j], pA[2 * j + 1]);
            wa1[j] = (int)b2(pA[8 + 2 * j], pA[9 + 2 * j]);
            wb0[j] = (int)b2(pB[2 * j], pB[2 * j + 1]);
            wb1[j] = (int)b2(pB[8 + 2 * j], pB[9 + 2 * j]);
        }
        bf16x8 pa0 = __builtin_bit_cast(bf16x8, wa0);
        bf16x8 pa1 = __builtin_bit_cast(bf16x8, wa1);
        bf16x8 pb0 = __builtin_bit_cast(bf16x8, wb0);
        bf16x8 pb1 = __builtin_bit_cast(bf16x8, wb1);
        // l sums on the MFMA pipe: C rows all equal per-q column sums
        laa = __builtin_amdgcn_mfma_f32_32x32x16_bf16(onesF, pa0, laa, 0, 0, 0);
        laa = __builtin_amdgcn_mfma_f32_32x32x16_bf16(onesF, pa1, laa, 0, 0, 0);
        lab = __builtin_amdgcn_mfma_f32_32x32x16_bf16(onesF, pb0, lab, 0, 0, 0);
        lab = __builtin_amdgcn_mfma_f32_32x32x16_bf16(onesF, pb1, lab, 0, 0, 0);
        // O^T (32 d x 32 q) += V^T . P, K-dim = keys (16 per mfma)
        o0 = __builtin_amdgcn_mfma_f32_32x32x16_bf16(vf0, pa0, o0, 0, 0, 0);
        o0 = __builtin_amdgcn_mfma_f32_32x32x16_bf16(vf1, pa1, o0, 0, 0, 0);
        o1 = __builtin_amdgcn_mfma_f32_32x32x16_bf16(vf0, pb0, o1, 0, 0, 0);
        o1 = __builtin_amdgcn_mfma_f32_32x32x16_bf16(vf1, pb1, o1, 0, 0, 0);
        kf0 = nk0; kf1 = nk1; vf0 = nv0; vf1 = nv1;
    }
    size_t rowa = (size_t)(part * 16 + bh) * 2048 + qa;
    _Float16* poa = PO + rowa * 32;
    _Float16* pob = PO + (rowa + 32) * 32;
#pragma unroll
    for (int cc = 0; cc < 4; cc++) {
        uint2 va, vb;
        va.x = h2(o0[4 * cc + 0], o0[4 * cc + 1]);
        va.y = h2(o0[4 * cc + 2], o0[4 * cc + 3]);
        vb.x = h2(o1[4 * cc + 0], o1[4 * cc + 1]);
        vb.y = h2(o1[4 * cc + 2], o1[4 * cc + 3]);
        *(uint2*)(poa + cc * 8 + hl * 4) = va;   // d = 8*cc + 4*hl + i
        *(uint2*)(pob + cc * 8 + hl * 4) = vb;
    }
    if (hl == 0) {
        PL[rowa] = laa[0];
        PL[rowa + 32] = lab[0];
    }
}

// ---------------- K3b: fused combine + out-projection ----------------
// 256 blocks x 16 q-rows. Phase 1: sum KSPLIT f16 partials per (q,d), normalize
// per head, stage O row-tile (16x256 bf16) in LDS (XOR-swizzled). Phase 2: 4
// waves GEMM 16x256 @ Wp^T (+bias) -> out f32.
__global__ __launch_bounds__(256) void combine_oproj(const _Float16* __restrict__ PO,
                                                     const float* __restrict__ PL,
                                                     const u16* __restrict__ Wp,
                                                     const float* __restrict__ bp,
                                                     float* __restrict__ out) {
    __shared__ u16 os[16 * 256];
    int t = threadIdx.x;
    int qloc = t >> 4, chunk = t & 15;        // chunk: 16 d per thread
    int R = blockIdx.x * 16 + qloc;           // global O row
    int b = R >> 11, q = R & 2047;
    int h = chunk >> 1;
    int d0 = chunk * 16;
    int d32 = d0 & 31;
    int bh = b * 8 + h;
    float acc[16];
#pragma unroll
    for (int j = 0; j < 16; j++) acc[j] = 0.f;
    float L = 0.f;
#pragma unroll
    for (int p = 0; p < KSPLIT; p++) {
        size_t i = ((size_t)(p * 16 + bh) << 11) + q;
        L += PL[i];
        const f16x8* src = (const f16x8*)(PO + i * 32 + d32);
        f32x8 x0 = __builtin_convertvector(src[0], f32x8);
        f32x8 x1 = __builtin_convertvector(src[1], f32x8);
#pragma unroll
        for (int e = 0; e < 8; e++) { acc[e] += x0[e]; acc[8 + e] += x1[e]; }
    }
    float inv = 1.0f / L;
    uint4 w0, w1;
    w0.x = b2(acc[0] * inv, acc[1] * inv);   w0.y = b2(acc[2] * inv, acc[3] * inv);
    w0.z = b2(acc[4] * inv, acc[5] * inv);   w0.w = b2(acc[6] * inv, acc[7] * inv);
    w1.x = b2(acc[8] * inv, acc[9] * inv);   w1.y = b2(acc[10] * inv, acc[11] * inv);
    w1.z = b2(acc[12] * inv, acc[13] * inv); w1.w = b2(acc[14] * inv, acc[15] * inv);
    int col16a = d0 >> 3;                     // 16B-chunk index (2 per thread)
    *(uint4*)((char*)os + qloc * 512 + ((col16a * 16) ^ ((qloc & 7) << 4))) = w0;
    *(uint4*)((char*)os + qloc * 512 + (((col16a + 1) * 16) ^ ((qloc & 7) << 4))) = w1;
    __syncthreads();
    int lane = t & 63, w = t >> 6;
    int lq = lane & 15, g = lane >> 4;
    int nb = w * 4;                           // 4 col-tiles of 16 per wave
    f32x4 acc4[4];
    f32x4 z = {0.f, 0.f, 0.f, 0.f};
#pragma unroll
    for (int j = 0; j < 4; j++) acc4[j] = z;
#pragma unroll
    for (int kk = 0; kk < 8; kk++) {
        bf16x8 aF = *(const bf16x8*)((const char*)os + lq * 512 +
                                     ((kk * 64 + g * 16) ^ ((lq & 7) << 4)));
#pragma unroll
        for (int j = 0; j < 4; j++) {
            bf16x8 bF = *(const bf16x8*)(Wp + (size_t)((nb + j) * 16 + lq) * 256 + kk * 32 + g * 8);
            acc4[j] = __builtin_amdgcn_mfma_f32_16x16x32_bf16(aF, bF, acc4[j], 0, 0, 0);
        }
    }
    int R0 = blockIdx.x * 16;
#pragma unroll
    for (int j = 0; j < 4; j++) {
        int col = (nb + j) * 16 + lq;
        float bias = bp[col];
#pragma unroll
        for (int r = 0; r < 4; r++) {
            int row = R0 + g * 4 + r;
            out[(size_t)row * 256 + col] = acc4[j][r] + bias;
        }
    }
}

extern "C" void kernel_launch(void* const* d_in, const int* in_sizes, int n_in,
                              void* d_out, int out_size, void* d_ws, size_t ws_size,
                              hipStream_t stream) {
    const float* xq = (const float*)d_in[0];
    const float* xk = (const float*)d_in[1];
    const float* xv = (const float*)d_in[2];
    const float* wq = (const float*)d_in[3];
    const float* wk = (const float*)d_in[4];
    const float* wv = (const float*)d_in[5];
    const float* wp = (const float*)d_in[6];
    const float* bp = (const float*)d_in[7];
    float* out = (float*)d_out;

    // workspace (u16 elems), 11 MB used:
    // W4 262144 | Qb 1M | K2 2M | V2 2M
    u16* wsb = (u16*)d_ws;
    u16* W4 = wsb;
    u16* WPb = wsb + 196608;
    u16* Qb = wsb + 262144;            // scale*log2e folded in
    u16* K2 = Qb + 1048576;            // [b][h][4096][32]
    u16* V2 = K2 + 2097152;            // [b][h][128][32][32] bit-swapped key perm

    // Flash partials live in the attn_save half of d_out (16.7M f32);
    // save_gemm runs LAST and fully overwrites this region.
    float* outw = out + 1048576;
    _Float16* PO = (_Float16*)outw;         // 8*16*2048*32 f16 = 33.6 MB (8.4M f32)
    float* PL = outw + 8388608;             //   262,144 f32  (total 8.65M < 16.7M)

    const float qalpha = 0.17677669529663687f * 1.4426950408889634f;  // scale*log2e

    cvt_w4<<<256, 256, 0, stream>>>(wq, wk, wv, wp, W4);
    proj_all<<<320, 256, 0, stream>>>(xq, xk, xv, W4, Qb, K2, V2, qalpha);

    attn_part<<<1024, 256, 0, stream>>>(Qb, K2, V2, PO, PL);
    combine_oproj<<<256, 256, 0, stream>>>(PO, PL, WPb, bp, out);

    save_gemm<<<1024, 256, 0, stream>>>(Qb, K2, out + 1048576);
}

// Round 17
// 108.627 us; speedup vs baseline: 1.0141x; 1.0141x over previous
//
#include <hip/hip_runtime.h>

typedef unsigned int u32;
typedef unsigned short u16;
typedef short bf16x8 __attribute__((ext_vector_type(8)));
typedef float f32x4 __attribute__((ext_vector_type(4)));
typedef float f32x8 __attribute__((ext_vector_type(8)));
typedef float f32x16 __attribute__((ext_vector_type(16)));
typedef int i32x4 __attribute__((ext_vector_type(4)));
typedef __bf16 bf16x2 __attribute__((ext_vector_type(2)));
typedef float f32x2 __attribute__((ext_vector_type(2)));
typedef _Float16 f16x2t __attribute__((ext_vector_type(2)));
typedef _Float16 f16x8 __attribute__((ext_vector_type(8)));

#define KSPLIT 4

// round-to-nearest-even f32 -> bf16 (bit trick, finite values)
__device__ __forceinline__ u32 pack2bf(float a, float b) {
    u32 ua = __float_as_uint(a), ub = __float_as_uint(b);
    ua = (ua + 0x7fffu + ((ua >> 16) & 1u)) >> 16;
    ub = (ub + 0x7fffu + ((ub >> 16) & 1u)) >> 16;
    return (ua & 0xffffu) | (ub << 16);
}
__device__ __forceinline__ u16 bf1(float a) {
    u32 ua = __float_as_uint(a);
    return (u16)((ua + 0x7fffu + ((ua >> 16) & 1u)) >> 16);
}
// pair convert: compiler emits v_cvt_pk_bf16_f32 (RNE)
__device__ __forceinline__ u32 b2(float a, float b) {
    f32x2 f; f[0] = a; f[1] = b;
    bf16x2 h = __builtin_convertvector(f, bf16x2);
    return __builtin_bit_cast(u32, h);
}
// pair convert f32 -> f16 (RNE)
__device__ __forceinline__ u32 h2(float a, float b) {
    f32x2 f; f[0] = a; f[1] = b;
    f16x2t h = __builtin_convertvector(f, f16x2t);
    return __builtin_bit_cast(u32, h);
}

// ---------------- K0: all four weights f32 -> bf16 in one launch ----------------
__global__ __launch_bounds__(256) void cvt_w4(const float* __restrict__ wq,
                                              const float* __restrict__ wk,
                                              const float* __restrict__ wv,
                                              const float* __restrict__ wp,
                                              u16* __restrict__ dst) {
    int i = blockIdx.x * 256 + threadIdx.x;   // 65536 float4-chunks total
    int which = i >> 14;
    int j = i & 16383;
    const float* s = which == 0 ? wq : which == 1 ? wk : which == 2 ? wv : wp;
    float4 a = ((const float4*)s)[j];
    uint2 v;
    v.x = pack2bf(a.x, a.y);
    v.y = pack2bf(a.z, a.w);
    ((uint2*)(dst + which * 65536))[j] = v;
}

// ---------------- K1: projections, flattened grid (64 Q + 128 K + 128 V blocks) ----
// mode 0: Qb = (scale*log2e) * xq @ Wq^T   [row][256]
// mode 1: K2 = xk @ Wk^T                    [b][h][n][32]  (attn layout, direct)
// mode 2: V2 = xv @ Wv^T                    [b][h][s32][32d][32pk], pk = key with
//         bits 2<->3 swapped (matches 32x32x16 PV B-fragment key ownership)
// Modes 0/1 use OPERAND-SWAPPED MFMA (C^T): thread owns X-row (m0+w*16+lq) and
// 4 consecutive output dims d = nt*16+g*4+r -> vectorized uint2 stores.
__global__ __launch_bounds__(256) void proj_all(const float* __restrict__ xq,
                                                const float* __restrict__ xk,
                                                const float* __restrict__ xv,
                                                const u16* __restrict__ W4,
                                                u16* __restrict__ Qb,
                                                u16* __restrict__ K2,
                                                u16* __restrict__ V2,
                                                float qalpha) {
    int bx = blockIdx.x;
    int mode = bx < 64 ? 0 : (bx < 192 ? 1 : 2);
    int xb = mode == 0 ? bx : (mode == 1 ? bx - 64 : bx - 192);
    const float* X = mode == 0 ? xq : mode == 1 ? xk : xv;
    const u16* Wb = W4 + mode * 65536;

    __shared__ u16 xs[64 * 256];
    int t = threadIdx.x;
    int m0 = xb * 64;
#pragma unroll
    for (int i = 0; i < 8; i++) {
        int c16 = t + 256 * i;
        int row = c16 >> 5, col16 = c16 & 31;
        const float4* src = (const float4*)(X + (size_t)(m0 + row) * 256 + col16 * 8);
        float4 a = src[0], b2v = src[1];
        uint4 v;
        v.x = pack2bf(a.x, a.y); v.y = pack2bf(a.z, a.w);
        v.z = pack2bf(b2v.x, b2v.y); v.w = pack2bf(b2v.z, b2v.w);
        int byteoff = row * 512 + ((col16 * 16) ^ ((row & 7) << 4));
        *(uint4*)((char*)xs + byteoff) = v;
    }
    __syncthreads();
    int lane = t & 63, w = t >> 6;
    int lq = lane & 15, g = lane >> 4;
    int rowA = w * 16 + lq;
    f32x4 acc[16];
    f32x4 z = {0.f, 0.f, 0.f, 0.f};
#pragma unroll
    for (int nt = 0; nt < 16; nt++) acc[nt] = z;
    if (mode < 2) {
        // swapped: C^T[d][m]; A = W fragment, B = X fragment (layouts symmetric)
#pragma unroll
        for (int kk = 0; kk < 8; kk++) {
            bf16x8 aF = *(const bf16x8*)((const char*)xs + rowA * 512 +
                                         ((kk * 64 + g * 16) ^ ((rowA & 7) << 4)));
#pragma unroll
            for (int nt = 0; nt < 16; nt++) {
                bf16x8 bF = *(const bf16x8*)(Wb + (size_t)(nt * 16 + lq) * 256 + kk * 32 + g * 8);
                acc[nt] = __builtin_amdgcn_mfma_f32_16x16x32_bf16(bF, aF, acc[nt], 0, 0, 0);
            }
        }
    } else {
#pragma unroll
        for (int kk = 0; kk < 8; kk++) {
            bf16x8 aF = *(const bf16x8*)((const char*)xs + rowA * 512 +
                                         ((kk * 64 + g * 16) ^ ((rowA & 7) << 4)));
#pragma unroll
            for (int nt = 0; nt < 16; nt++) {
                bf16x8 bF = *(const bf16x8*)(Wb + (size_t)(nt * 16 + lq) * 256 + kk * 32 + g * 8);
                acc[nt] = __builtin_amdgcn_mfma_f32_16x16x32_bf16(aF, bF, acc[nt], 0, 0, 0);
            }
        }
    }
    if (mode == 0) {
        int mrow = m0 + w * 16 + lq;
        u16* dst = Qb + (size_t)mrow * 256 + g * 4;
#pragma unroll
        for (int nt = 0; nt < 16; nt++) {
            uint2 v;
            v.x = pack2bf(acc[nt][0] * qalpha, acc[nt][1] * qalpha);
            v.y = pack2bf(acc[nt][2] * qalpha, acc[nt][3] * qalpha);
            *(uint2*)(dst + nt * 16) = v;
        }
    } else if (mode == 1) {
        int m = m0 + w * 16 + lq;
        int b = m >> 12, n = m & 4095;
#pragma unroll
        for (int nt = 0; nt < 16; nt++) {
            int d = nt * 16 + g * 4;           // 4-aligned, never crosses 32-boundary
            int h = d >> 5, d32 = d & 31;
            uint2 v;
            v.x = pack2bf(acc[nt][0], acc[nt][1]);
            v.y = pack2bf(acc[nt][2], acc[nt][3]);
            *(uint2*)(K2 + ((size_t)(b * 8 + h) * 4096 + n) * 32 + d32) = v;
        }
    } else {
        // V: keys m..m+3 at dim d -> permuted tile store (swap bits 2,3 of key&31)
        int m = m0 + w * 16 + g * 4;
        int b = m >> 12, n = m & 4095;
        int s = n >> 5;
        int t5 = n & 31;                                   // bits 0,1 are zero
        int pklo = (t5 & 19) | ((t5 << 1) & 8) | ((t5 >> 1) & 4);
#pragma unroll
        for (int nt = 0; nt < 16; nt++) {
            int d = nt * 16 + lq;
            int h = d >> 5, d32 = d & 31;
            uint2 v;
            v.x = pack2bf(acc[nt][0], acc[nt][1]);
            v.y = pack2bf(acc[nt][2], acc[nt][3]);
            *(uint2*)(V2 + ((((size_t)(b * 8 + h) * 128 + s) * 32 + d32) * 32 + pklo)) = v;
        }
    }
}

// ---------------- K2g: attn_save = (Qb . K^T) * 0.125*ln2, f32 out (runs LAST) ----
// 32x32x16 MFMA, depth-1 register prefetch over kk, setprio around MFMA cluster.
// K-dim 256 = 16 steps; head h = kk>>1, within-head offset (kk&1)*16.
// 1-D grid with XCD swizzle: chunk of 128 consecutive tiles per XCD (1024%8==0).
__global__ __launch_bounds__(256) void save_gemm(const u16* __restrict__ Qb,
                                                 const u16* __restrict__ K2,
                                                 float* __restrict__ sv) {
    const float SAVE = 0.125f * 0.69314718055994530942f;
    int id = blockIdx.x;                       // 0..1023
    int sw = (id & 7) * 128 + (id >> 3);       // bijective XCD chunking
    int b = sw >> 9;
    int r = sw & 511;
    int m0 = (r >> 5) * 128;                   // 16 m-tiles of 128
    int n0 = (r & 31) * 128;                   // 32 n-tiles of 128
    int t = threadIdx.x, lane = t & 63, wv = t >> 6;
    int wr = wv >> 1, wc = wv & 1;
    int l32 = lane & 31, hl = lane >> 5;
    const u16* Q = Qb + (size_t)b * 2048 * 256;
    const u16* Kb = K2 + (size_t)b * 8 * 4096 * 32;
    const u16* Abase = Q + (size_t)(m0 + wr * 64 + l32) * 256 + hl * 8;
    const u16* Bbase = Kb + (size_t)(n0 + wc * 64 + l32) * 32 + hl * 8;
    f32x16 acc[2][2];
    f32x16 z16 = {};
#pragma unroll
    for (int mt = 0; mt < 2; mt++)
#pragma unroll
        for (int nt = 0; nt < 2; nt++) acc[mt][nt] = z16;
    bf16x8 aF0 = *(const bf16x8*)(Abase);
    bf16x8 aF1 = *(const bf16x8*)(Abase + 32 * 256);
    bf16x8 bF0 = *(const bf16x8*)(Bbase);
    bf16x8 bF1 = *(const bf16x8*)(Bbase + 32 * 32);
#pragma unroll
    for (int kk = 0; kk < 16; kk++) {
        int nx = kk < 15 ? kk + 1 : 15;
        const u16* na = Abase + nx * 16;
        const u16* nb = Bbase + (size_t)(nx >> 1) * 131072 + (nx & 1) * 16;
        bf16x8 a0 = *(const bf16x8*)(na);
        bf16x8 a1 = *(const bf16x8*)(na + 32 * 256);
        bf16x8 b0 = *(const bf16x8*)(nb);
        bf16x8 b1 = *(const bf16x8*)(nb + 32 * 32);
        __builtin_amdgcn_s_setprio(1);
        acc[0][0] = __builtin_amdgcn_mfma_f32_32x32x16_bf16(aF0, bF0, acc[0][0], 0, 0, 0);
        acc[0][1] = __builtin_amdgcn_mfma_f32_32x32x16_bf16(aF0, bF1, acc[0][1], 0, 0, 0);
        acc[1][0] = __builtin_amdgcn_mfma_f32_32x32x16_bf16(aF1, bF0, acc[1][0], 0, 0, 0);
        acc[1][1] = __builtin_amdgcn_mfma_f32_32x32x16_bf16(aF1, bF1, acc[1][1], 0, 0, 0);
        __builtin_amdgcn_s_setprio(0);
        aF0 = a0; aF1 = a1; bF0 = b0; bF1 = b1;
    }
#pragma unroll
    for (int mt = 0; mt < 2; mt++) {
#pragma unroll
        for (int nt = 0; nt < 2; nt++) {
            int col = n0 + wc * 64 + nt * 32 + l32;
#pragma unroll
            for (int rg = 0; rg < 16; rg++) {
                int row = m0 + wr * 64 + mt * 32 + (rg & 3) + 8 * (rg >> 2) + 4 * hl;
                sv[((size_t)b * 2048 + row) * 4096 + col] = acc[mt][nt][rg] * SAVE;
            }
        }
    }
}

// ---------------- K3: flash attention partial, 32x32x16 MFMA, 64 q/wave --------------
// 1-D grid 512 blocks (id&7 = h -> XCD-local K/V), 256 thr. Wave: 64 q (2 groups
// of 32), 1024 keys (KSPLIT=4). No LDS, no barriers, no running max; exp2 direct.
// Depth-1 register prefetch of next subtile's K/V fragments. l via ones-A MFMA.
__global__ __launch_bounds__(256, 2) void attn_part(const u16* __restrict__ Qb,
                                                    const u16* __restrict__ K2,
                                                    const u16* __restrict__ V2,
                                                    _Float16* __restrict__ PO,
                                                    float* __restrict__ PL) {
    int id = blockIdx.x;
    int h = id & 7;
    int r0 = id >> 3;
    int qblk = r0 & 7;
    int b = (r0 >> 3) & 1;
    int part = r0 >> 4;                       // 0..3
    int bh = b * 8 + h;
    int t = threadIdx.x, lane = t & 63, w = t >> 6;
    int lq = lane & 31, hl = lane >> 5;
    int qa = qblk * 256 + w * 64 + lq;        // group 0; group 1 = qa+32
    const u16* Qrow = Qb + ((size_t)(b * 2048 + qa)) * 256 + h * 32 + hl * 8;
    bf16x8 qf00 = *(const bf16x8*)(Qrow);
    bf16x8 qf01 = *(const bf16x8*)(Qrow + 16);
    bf16x8 qf10 = *(const bf16x8*)(Qrow + 32 * 256);
    bf16x8 qf11 = *(const bf16x8*)(Qrow + 32 * 256 + 16);
    const u16* Kh = K2 + ((size_t)bh * 4096 + part * 1024 + lq) * 32 + hl * 8;
    const u16* Vh = V2 + (size_t)bh * 131072 + part * 32768 + lq * 32 + hl * 8;
    f32x16 z16 = {};
    f32x16 o0 = z16, o1 = z16, laa = z16, lab = z16;
    const short ONE = (short)0x3F80;          // bf16 1.0
    bf16x8 onesF = {ONE, ONE, ONE, ONE, ONE, ONE, ONE, ONE};
    // subtile i (i=0..31): keys [i*32, i*32+32). K stride 1024 u16, V stride 1024 u16.
    bf16x8 kf0 = *(const bf16x8*)(Kh);
    bf16x8 kf1 = *(const bf16x8*)(Kh + 16);
    bf16x8 vf0 = *(const bf16x8*)(Vh);
    bf16x8 vf1 = *(const bf16x8*)(Vh + 16);
    for (int i = 0; i < 32; ++i) {
        // prefetch subtile i+1 (clamped; last iter reloads i=31, harmless)
        int nx = i < 31 ? i + 1 : 31;
        const u16* nkp = Kh + nx * 1024;
        const u16* nvp = Vh + nx * 1024;
        bf16x8 nk0 = *(const bf16x8*)(nkp);
        bf16x8 nk1 = *(const bf16x8*)(nkp + 16);
        bf16x8 nv0 = *(const bf16x8*)(nvp);
        bf16x8 nv1 = *(const bf16x8*)(nvp + 16);
        // S^T tiles (32 keys x 32 q), K-dim = d
        f32x16 sA = __builtin_amdgcn_mfma_f32_32x32x16_bf16(kf0, qf00, z16, 0, 0, 0);
        sA = __builtin_amdgcn_mfma_f32_32x32x16_bf16(kf1, qf01, sA, 0, 0, 0);
        f32x16 sB = __builtin_amdgcn_mfma_f32_32x32x16_bf16(kf0, qf10, z16, 0, 0, 0);
        sB = __builtin_amdgcn_mfma_f32_32x32x16_bf16(kf1, qf11, sB, 0, 0, 0);
        // p = exp2(S), pack to PV B-fragments
        float pA[16], pB[16];
#pragma unroll
        for (int k = 0; k < 16; k++) pA[k] = __builtin_amdgcn_exp2f(sA[k]);
#pragma unroll
        for (int k = 0; k < 16; k++) pB[k] = __builtin_amdgcn_exp2f(sB[k]);
        i32x4 wa0, wa1, wb0, wb1;
#pragma unroll
        for (int j = 0; j < 4; j++) {
            wa0[j] = (int)b2(pA[2 * j], pA[2 * j + 1]);
            wa1[j] = (int)b2(pA[8 + 2 * j], pA[9 + 2 * j]);
            wb0[j] = (int)b2(pB[2 * j], pB[2 * j + 1]);
            wb1[j] = (int)b2(pB[8 + 2 * j], pB[9 + 2 * j]);
        }
        bf16x8 pa0 = __builtin_bit_cast(bf16x8, wa0);
        bf16x8 pa1 = __builtin_bit_cast(bf16x8, wa1);
        bf16x8 pb0 = __builtin_bit_cast(bf16x8, wb0);
        bf16x8 pb1 = __builtin_bit_cast(bf16x8, wb1);
        // l sums on the MFMA pipe: C rows all equal per-q column sums
        laa = __builtin_amdgcn_mfma_f32_32x32x16_bf16(onesF, pa0, laa, 0, 0, 0);
        laa = __builtin_amdgcn_mfma_f32_32x32x16_bf16(onesF, pa1, laa, 0, 0, 0);
        lab = __builtin_amdgcn_mfma_f32_32x32x16_bf16(onesF, pb0, lab, 0, 0, 0);
        lab = __builtin_amdgcn_mfma_f32_32x32x16_bf16(onesF, pb1, lab, 0, 0, 0);
        // O^T (32 d x 32 q) += V^T . P, K-dim = keys (16 per mfma)
        o0 = __builtin_amdgcn_mfma_f32_32x32x16_bf16(vf0, pa0, o0, 0, 0, 0);
        o0 = __builtin_amdgcn_mfma_f32_32x32x16_bf16(vf1, pa1, o0, 0, 0, 0);
        o1 = __builtin_amdgcn_mfma_f32_32x32x16_bf16(vf0, pb0, o1, 0, 0, 0);
        o1 = __builtin_amdgcn_mfma_f32_32x32x16_bf16(vf1, pb1, o1, 0, 0, 0);
        kf0 = nk0; kf1 = nk1; vf0 = nv0; vf1 = nv1;
    }
    size_t rowa = (size_t)(part * 16 + bh) * 2048 + qa;
    _Float16* poa = PO + rowa * 32;
    _Float16* pob = PO + (rowa + 32) * 32;
#pragma unroll
    for (int cc = 0; cc < 4; cc++) {
        uint2 va, vb;
        va.x = h2(o0[4 * cc + 0], o0[4 * cc + 1]);
        va.y = h2(o0[4 * cc + 2], o0[4 * cc + 3]);
        vb.x = h2(o1[4 * cc + 0], o1[4 * cc + 1]);
        vb.y = h2(o1[4 * cc + 2], o1[4 * cc + 3]);
        *(uint2*)(poa + cc * 8 + hl * 4) = va;   // d = 8*cc + 4*hl + i
        *(uint2*)(pob + cc * 8 + hl * 4) = vb;
    }
    if (hl == 0) {
        PL[rowa] = laa[0];
        PL[rowa + 32] = lab[0];
    }
}

// ---------------- K3b: fused combine + out-projection ----------------
// 256 blocks x 16 q-rows. Phase 1: sum KSPLIT f16 partials per (q,d), normalize
// per head, stage O row-tile (16x256 bf16) in LDS (XOR-swizzled). Phase 2: 4
// waves GEMM 16x256 @ Wp^T (+bias) -> out f32.
__global__ __launch_bounds__(256) void combine_oproj(const _Float16* __restrict__ PO,
                                                     const float* __restrict__ PL,
                                                     const u16* __restrict__ Wp,
                                                     const float* __restrict__ bp,
                                                     float* __restrict__ out) {
    __shared__ u16 os[16 * 256];
    int t = threadIdx.x;
    int qloc = t >> 4, chunk = t & 15;        // chunk: 16 d per thread
    int R = blockIdx.x * 16 + qloc;           // global O row
    int b = R >> 11, q = R & 2047;
    int h = chunk >> 1;
    int d0 = chunk * 16;
    int d32 = d0 & 31;
    int bh = b * 8 + h;
    float acc[16];
#pragma unroll
    for (int j = 0; j < 16; j++) acc[j] = 0.f;
    float L = 0.f;
#pragma unroll
    for (int p = 0; p < KSPLIT; p++) {
        size_t i = ((size_t)(p * 16 + bh) << 11) + q;
        L += PL[i];
        const f16x8* src = (const f16x8*)(PO + i * 32 + d32);
        f32x8 x0 = __builtin_convertvector(src[0], f32x8);
        f32x8 x1 = __builtin_convertvector(src[1], f32x8);
#pragma unroll
        for (int e = 0; e < 8; e++) { acc[e] += x0[e]; acc[8 + e] += x1[e]; }
    }
    float inv = 1.0f / L;
    uint4 w0, w1;
    w0.x = b2(acc[0] * inv, acc[1] * inv);   w0.y = b2(acc[2] * inv, acc[3] * inv);
    w0.z = b2(acc[4] * inv, acc[5] * inv);   w0.w = b2(acc[6] * inv, acc[7] * inv);
    w1.x = b2(acc[8] * inv, acc[9] * inv);   w1.y = b2(acc[10] * inv, acc[11] * inv);
    w1.z = b2(acc[12] * inv, acc[13] * inv); w1.w = b2(acc[14] * inv, acc[15] * inv);
    int col16a = d0 >> 3;                     // 16B-chunk index (2 per thread)
    *(uint4*)((char*)os + qloc * 512 + ((col16a * 16) ^ ((qloc & 7) << 4))) = w0;
    *(uint4*)((char*)os + qloc * 512 + (((col16a + 1) * 16) ^ ((qloc & 7) << 4))) = w1;
    __syncthreads();
    int lane = t & 63, w = t >> 6;
    int lq = lane & 15, g = lane >> 4;
    int nb = w * 4;                           // 4 col-tiles of 16 per wave
    f32x4 acc4[4];
    f32x4 z = {0.f, 0.f, 0.f, 0.f};
#pragma unroll
    for (int j = 0; j < 4; j++) acc4[j] = z;
#pragma unroll
    for (int kk = 0; kk < 8; kk++) {
        bf16x8 aF = *(const bf16x8*)((const char*)os + lq * 512 +
                                     ((kk * 64 + g * 16) ^ ((lq & 7) << 4)));
#pragma unroll
        for (int j = 0; j < 4; j++) {
            bf16x8 bF = *(const bf16x8*)(Wp + (size_t)((nb + j) * 16 + lq) * 256 + kk * 32 + g * 8);
            acc4[j] = __builtin_amdgcn_mfma_f32_16x16x32_bf16(aF, bF, acc4[j], 0, 0, 0);
        }
    }
    int R0 = blockIdx.x * 16;
#pragma unroll
    for (int j = 0; j < 4; j++) {
        int col = (nb + j) * 16 + lq;
        float bias = bp[col];
#pragma unroll
        for (int r = 0; r < 4; r++) {
            int row = R0 + g * 4 + r;
            out[(size_t)row * 256 + col] = acc4[j][r] + bias;
        }
    }
}

extern "C" void kernel_launch(void* const* d_in, const int* in_sizes, int n_in,
                              void* d_out, int out_size, void* d_ws, size_t ws_size,
                              hipStream_t stream) {
    const float* xq = (const float*)d_in[0];
    const float* xk = (const float*)d_in[1];
    const float* xv = (const float*)d_in[2];
    const float* wq = (const float*)d_in[3];
    const float* wk = (const float*)d_in[4];
    const float* wv = (const float*)d_in[5];
    const float* wp = (const float*)d_in[6];
    const float* bp = (const float*)d_in[7];
    float* out = (float*)d_out;

    // workspace (u16 elems), 11 MB used:
    // W4 262144 | Qb 1M | K2 2M | V2 2M
    u16* wsb = (u16*)d_ws;
    u16* W4 = wsb;
    u16* WPb = wsb + 196608;
    u16* Qb = wsb + 262144;            // scale*log2e folded in
    u16* K2 = Qb + 1048576;            // [b][h][4096][32]
    u16* V2 = K2 + 2097152;            // [b][h][128][32][32] bit-swapped key perm

    // Flash partials live in the attn_save half of d_out (16.7M f32);
    // save_gemm runs LAST and fully overwrites this region.
    float* outw = out + 1048576;
    _Float16* PO = (_Float16*)outw;         // 4*16*2048*32 f16 = 8.4 MB
    float* PL = outw + 2097152;             //   131,072 f32

    const float qalpha = 0.17677669529663687f * 1.4426950408889634f;  // scale*log2e

    cvt_w4<<<256, 256, 0, stream>>>(wq, wk, wv, wp, W4);
    proj_all<<<320, 256, 0, stream>>>(xq, xk, xv, W4, Qb, K2, V2, qalpha);

    attn_part<<<512, 256, 0, stream>>>(Qb, K2, V2, PO, PL);
    combine_oproj<<<256, 256, 0, stream>>>(PO, PL, WPb, bp, out);

    save_gemm<<<1024, 256, 0, stream>>>(Qb, K2, out + 1048576);
}